// Round 15
// baseline (318.643 us; speedup 1.0000x reference)
//
#include <hip/hip_runtime.h>

#define NT 20        // time steps
#define BT 4096      // batch
#define HD 128       // hidden
#define RT 81920     // total rows = K*B = 20*4096
#define RB 128       // rows per block (two 64-row halves)

typedef _Float16 half8 __attribute__((ext_vector_type(8)));
typedef _Float16 half2v __attribute__((ext_vector_type(2)));
typedef float f32x4 __attribute__((ext_vector_type(4)));
typedef float f32x2 __attribute__((ext_vector_type(2)));
typedef unsigned u32x4 __attribute__((ext_vector_type(4)));

#if defined(__has_builtin)
#  if __has_builtin(__builtin_amdgcn_fdot2)
#    define HAVE_FDOT2 1
#  endif
#endif

__device__ __forceinline__ float clamp01(float x) {
  return fminf(fmaxf(x, 0.0f), 1.0f);
}
__device__ __forceinline__ float htanh(float x) {
  return fminf(fmaxf(x, -1.0f), 1.0f);
}

__device__ __forceinline__ float dot2(half2v a, half2v b, float c) {
#ifdef HAVE_FDOT2
  return __builtin_amdgcn_fdot2(a, b, c, false);
#else
  return fmaf((float)a[0], (float)b[0], fmaf((float)a[1], (float)b[1], c));
#endif
}

// load 8 consecutive f32, scale, convert to f16x8 fragment
__device__ __forceinline__ half8 ldcvt8s(const float* __restrict__ p, float s) {
  f32x4 a = *(const f32x4*)p;
  f32x4 b = *(const f32x4*)(p + 4);
  half8 r;
  r[0] = (_Float16)(a[0] * s); r[1] = (_Float16)(a[1] * s);
  r[2] = (_Float16)(a[2] * s); r[3] = (_Float16)(a[3] * s);
  r[4] = (_Float16)(b[0] * s); r[5] = (_Float16)(b[1] * s);
  r[6] = (_Float16)(b[2] * s); r[7] = (_Float16)(b[3] * s);
  return r;
}
__device__ __forceinline__ half8 ldcvt8(const float* __restrict__ p) {
  return ldcvt8s(p, 1.0f);
}

// LDS-visibility-only barrier (no vmcnt(0) drain; fold stores stay in flight)
__device__ __forceinline__ void lds_barrier() {
  __builtin_amdgcn_sched_barrier(0);
  asm volatile("s_waitcnt lgkmcnt(0)" ::: "memory");
  __builtin_amdgcn_s_barrier();
  __builtin_amdgcn_sched_barrier(0);
}

// Persistent LSTM decoder, 128 rows/block (two 64-row halves), 8 waves.
// R14 analysis: 1280 blocks at 1 resident block/CU = 5 sequential rounds,
// per-step critical path ~8.5k cyc vs ~2k component floor -> wall is
// rounds x steps x fixed-latency CP, all pipes <35%. R15 halves the round
// count: each j processes tile mm (half0) AND tile mm+4 (half1) as two
// independent MFMA chains sharing the same B fragments (8 acc chains of
// depth 5 = ample ILP at 2 waves/SIMD; B-operand reuse is free). Grid 640
// = 2.5 rounds. Per-step work doubles but rides the same latency.
// Register ledger (the recurring killer): bW 64 + bAug 16 + acc 32 +
// cst 32 + A 40 + addr/misc ~30 = ~214 <= 256 at (512,2). wfr hoist
// DROPPED (fold reads W_out from LDS) to keep slack.
// Numerics = R12 verified path per row (absmax 3.9e-3).
// Wave w owns hidden slice [16w,16w+16) of each half's 64x512 gate GEMM;
// gate cols 128n+16w+(l&15), lane-local D-layout (col=l&15, row=4(l>>4)+reg).
// h: LDS f16 double-buffered [128][128] per parity, swizzle byte^=(row&7)<<4.
// c: registers cst[half][j] (compile-time). hsig prefold as before.
// Fold: wave w folds (tile wm, col wc) of both halves at j==3.
__global__ __launch_bounds__(512, 2) void decoder_kernel(
    const float* __restrict__ obs, const float* __restrict__ pred,
    const float* __restrict__ Wm1, const float* __restrict__ bm1,
    const float* __restrict__ Wm2, const float* __restrict__ bm2,
    const float* __restrict__ W_ih, const float* __restrict__ W_hh,
    const float* __restrict__ b_ih, const float* __restrict__ b_hh,
    const float* __restrict__ W_out, const float* __restrict__ b_out,
    float* __restrict__ outp)
{
  __shared__ __align__(16) char lds[76288];
  const int tid = threadIdx.x;
  const int w   = tid >> 6;       // wave id 0..7
  const int l   = tid & 63;
  const int l15 = l & 15;
  const int lg  = l >> 4;         // lane group 0..3
  const int wm  = w & 3;          // fold m-tile
  const int wc  = w >> 2;         // fold output column
  const int r0  = blockIdx.x * RB;
  const int b0  = r0 & (BT - 1);

  char* const buf0 = lds;             // h buffer parity 0 (32KB: [128]x256B)
  char* const h1l  = lds + 32768;     // parity-1 h buffer; aliases MLP mid acts
  char* const obsl = lds + 65536;     // obs staged: [20][128] packed f16x2 (10KB)
  char* const wol  = lds + 75776;     // W_out f16 [2][128] (512B)

  const f32x4 fzero = {0.f, 0.f, 0.f, 0.f};
  const float SCL = 1.0f / 6.0f;

  const int rdmask = (l15 & 7) << 4;
  const int arow  = l15 * 256;              // A-read row byte (within half-tile)
  const int base0 = (16 * lg) ^ rdmask;     // A-read k byte; ao[kt]=(64*kt)^base0
  const int wcol2 = 32 * w + 2 * l15;       // h-write col byte (pre-swizzle)

  int wbase[4];
#pragma unroll
  for (int reg = 0; reg < 4; ++reg) {
    int rr = 4 * lg + reg;
    wbase[reg] = rr * 256 + (wcol2 ^ ((rr & 7) << 4));
  }

  // ---- stage W_out (f16), obs (packed f16x2, [20][128]) ----
  if (tid < 256) ((_Float16*)wol)[tid] = (_Float16)W_out[tid];
  for (int i = tid; i < NT * RB; i += 512) {
    int t = i >> 7, row = i & 127;
    int tp = (t > 0) ? t - 1 : 0;
    f32x2 xv = *(const f32x2*)(obs + ((size_t)tp * BT + b0 + row) * 2);
    half2v hp; hp[0] = (_Float16)xv[0]; hp[1] = (_Float16)xv[1];
    *(unsigned*)(obsl + (size_t)i * 4) = __builtin_bit_cast(unsigned, hp);
  }

  // ---------------- Prologue: h0 = MLP(pred), 128 rows ----------------
  // GEMM1: h1[128x64] = leaky_relu(pred @ Wm1^T + bm1).
  // wave w: m = wm (half0), wm+4 (half1); n = 2wc+{0,1}
  {
    half8 a1[2][4], b1[2][4];
#pragma unroll
    for (int h = 0; h < 2; ++h)
#pragma unroll
      for (int kt = 0; kt < 4; ++kt)
        a1[h][kt] = ldcvt8(pred + (size_t)(r0 + 64 * h + 16 * wm + l15) * HD + kt * 32 + lg * 8);
#pragma unroll
    for (int j = 0; j < 2; ++j)
#pragma unroll
      for (int kt = 0; kt < 4; ++kt)
        b1[j][kt] = ldcvt8(Wm1 + (l15 + 16 * (2 * wc + j)) * HD + kt * 32 + lg * 8);
    f32x4 acc1[2][2] = {{fzero, fzero}, {fzero, fzero}};
#pragma unroll
    for (int kt = 0; kt < 4; ++kt)
#pragma unroll
      for (int h = 0; h < 2; ++h)
#pragma unroll
        for (int j = 0; j < 2; ++j)
          acc1[h][j] = __builtin_amdgcn_mfma_f32_16x16x32_f16(a1[h][kt], b1[j][kt], acc1[h][j], 0, 0, 0);
#pragma unroll
    for (int h = 0; h < 2; ++h)
#pragma unroll
      for (int j = 0; j < 2; ++j) {
        int c = l15 + 16 * (2 * wc + j);
        float bb = bm1[c];
#pragma unroll
        for (int reg = 0; reg < 4; ++reg) {
          int row = 64 * h + 16 * wm + 4 * lg + reg;
          float v = acc1[h][j][reg] + bb;
          v = v >= 0.f ? v : 0.01f * v;
          *(_Float16*)(h1l + row * 128 + ((2 * c) ^ ((row & 7) << 4))) = (_Float16)v;
        }
      }
  }
  __syncthreads();
  // GEMM2: h0[128x128] = h1 @ Wm2^T + bm2 -> buf0.
  // wave w: m = wm, wm+4; n = 4wc+{0..3}
  {
    half8 a2[2][2], b2[4][2];
#pragma unroll
    for (int h = 0; h < 2; ++h)
#pragma unroll
      for (int kt = 0; kt < 2; ++kt) {
        int row = 64 * h + 16 * wm + l15;
        a2[h][kt] = *(const half8*)(h1l + row * 128 + ((64 * kt + 16 * lg) ^ rdmask));
      }
#pragma unroll
    for (int j = 0; j < 4; ++j)
#pragma unroll
      for (int kt = 0; kt < 2; ++kt)
        b2[j][kt] = ldcvt8(Wm2 + (l15 + 16 * (4 * wc + j)) * 64 + kt * 32 + lg * 8);
    f32x4 acc2[2][4];
#pragma unroll
    for (int h = 0; h < 2; ++h)
#pragma unroll
      for (int j = 0; j < 4; ++j) acc2[h][j] = fzero;
#pragma unroll
    for (int kt = 0; kt < 2; ++kt)
#pragma unroll
      for (int h = 0; h < 2; ++h)
#pragma unroll
        for (int j = 0; j < 4; ++j)
          acc2[h][j] = __builtin_amdgcn_mfma_f32_16x16x32_f16(a2[h][kt], b2[j][kt], acc2[h][j], 0, 0, 0);
#pragma unroll
    for (int h = 0; h < 2; ++h)
#pragma unroll
      for (int j = 0; j < 4; ++j) {
        int c = l15 + 16 * (4 * wc + j);
        float bb = bm2[c];
#pragma unroll
        for (int reg = 0; reg < 4; ++reg) {
          int row = 64 * h + 16 * wm + 4 * lg + reg;
          float v = acc2[h][j][reg] + bb;
          *(_Float16*)(buf0 + row * 256 + ((2 * c) ^ ((row & 7) << 4))) = (_Float16)v;
        }
      }
  }

  // ---- steady-state per-wave constants ----
  half8 bW[4][4];
  half8 bAug[4];
#pragma unroll
  for (int n = 0; n < 4; ++n) {
    const float s = (n == 2) ? 1.0f : SCL;
    int g = 128 * n + 16 * w + l15;
#pragma unroll
    for (int kt = 0; kt < 4; ++kt)
      bW[n][kt] = ldcvt8s(W_hh + (size_t)g * HD + kt * 32 + lg * 8, s);
    half2v t2;
    t2[0] = (_Float16)(W_ih[g * 2 + 0] * s);
    t2[1] = (_Float16)(W_ih[g * 2 + 1] * s);
    float bs = b_ih[g] + b_hh[g];
    half2v t3;
    t3[0] = (_Float16)((n == 2) ? bs : bs * SCL + 0.5f);
    t3[1] = (_Float16)0.0f;
    unsigned v0 = (lg == 0) ? __builtin_bit_cast(unsigned, t2) : 0u;
    unsigned v1 = (lg == 0) ? __builtin_bit_cast(unsigned, t3) : 0u;
    u32x4 bu = {v0, v1, 0u, 0u};
    bAug[n] = __builtin_bit_cast(half8, bu);
  }
  const float bo = wc ? b_out[1] : b_out[0];

  // c-state: cst[half][j], all compile-time indices
  f32x4 cst[2][4];
#pragma unroll
  for (int h = 0; h < 2; ++h)
#pragma unroll
    for (int j = 0; j < 4; ++j) cst[h][j] = fzero;

  __syncthreads();  // h0/obs/wol visible; h1l reads done (step0 writes alias)

  // ---------------- 20 recurrent steps ----------------
  for (int t = 0; t < NT; ++t) {
    char* const brd = lds + ((t & 1) << 15);
    char* const bwr = lds + (((t & 1) ^ 1) << 15);

#pragma unroll
    for (int j = 0; j < 4; ++j) {
      const int mm = (wm + 1 + j) & 3;   // fold tiles (mm==wm) at j==3

      // A-fragments for both halves (tile mm and tile mm+4)
      half8 A0[5], A1[5];
#pragma unroll
      for (int kt = 0; kt < 4; ++kt) {
        A0[kt] = *(const half8*)(brd + mm * 4096 + arow + ((64 * kt) ^ base0));
        A1[kt] = *(const half8*)(brd + (mm + 4) * 4096 + arow + ((64 * kt) ^ base0));
      }
      {
        unsigned xv0 = *(const unsigned*)(obsl + ((t << 7) + (mm << 4) + l15) * 4);
        unsigned xv1 = *(const unsigned*)(obsl + ((t << 7) + ((mm + 4) << 4) + l15) * 4);
        unsigned u1c = (lg == 0) ? 0x00003C00u : 0u;  // f16 1.0 in elem 2
        u32x4 xu0 = {(lg == 0) ? xv0 : 0u, u1c, 0u, 0u};
        u32x4 xu1 = {(lg == 0) ? xv1 : 0u, u1c, 0u, 0u};
        A0[4] = __builtin_bit_cast(half8, xu0);
        A1[4] = __builtin_bit_cast(half8, xu1);
      }

      // MFMA clusters, both halves interleaved (8 independent acc chains)
      f32x4 acc0[4] = {fzero, fzero, fzero, fzero};
      f32x4 acc1[4] = {fzero, fzero, fzero, fzero};
      __builtin_amdgcn_s_setprio(1);
#pragma unroll
      for (int kt = 0; kt < 5; ++kt) {
#pragma unroll
        for (int n = 0; n < 4; ++n) {
          const half8 bfrag = (kt < 4) ? bW[n][kt] : bAug[n];
          acc0[n] = __builtin_amdgcn_mfma_f32_16x16x32_f16(A0[kt], bfrag, acc0[n], 0, 0, 0);
          acc1[n] = __builtin_amdgcn_mfma_f32_16x16x32_f16(A1[kt], bfrag, acc1[n], 0, 0, 0);
        }
      }
      __builtin_amdgcn_s_setprio(0);

      // fold both halves at j==3 (tiles wm, wm+4): out[t-1]
      if (j == 3 && t > 0) {
        float p0 = 0.f, p1 = 0.f;
#pragma unroll
        for (int kt = 0; kt < 4; ++kt) {
          const half8 wf = *(const half8*)(wol + wc * 256 + kt * 64 + lg * 16);
          const half8 a0 = A0[kt], a1 = A1[kt];
#pragma unroll
          for (int pp = 0; pp < 4; ++pp) {
            half2v wa; wa[0] = wf[2 * pp]; wa[1] = wf[2 * pp + 1];
            half2v h0; h0[0] = a0[2 * pp]; h0[1] = a0[2 * pp + 1];
            half2v h1; h1[0] = a1[2 * pp]; h1[1] = a1[2 * pp + 1];
            p0 = dot2(h0, wa, p0);
            p1 = dot2(h1, wa, p1);
          }
        }
        p0 += __shfl_xor(p0, 16, 64); p0 += __shfl_xor(p0, 32, 64);
        p1 += __shfl_xor(p1, 16, 64); p1 += __shfl_xor(p1, 32, 64);
        if (l < 16) {
          size_t base = (size_t)(t - 1) * (RT * 2);
          outp[base + (size_t)(r0 + 16 * wm + l) * 2 + wc] = p0 + bo;
          outp[base + (size_t)(r0 + 64 + 16 * wm + l) * 2 + wc] = p1 + bo;
        }
      }

      // fused LSTM update, both halves (lane-local, compile-time cst idx)
#pragma unroll
      for (int h = 0; h < 2; ++h) {
        const f32x4* ac = h ? acc1 : acc0;
        f32x4 cn4;
#pragma unroll
        for (int reg = 0; reg < 4; ++reg) {
          float i_ = clamp01(ac[0][reg]);
          float f_ = clamp01(ac[1][reg]);
          float g_ = htanh(ac[2][reg]);
          float o_ = clamp01(ac[3][reg]);
          float cn = fmaf(f_, cst[h][j][reg], i_ * g_);
          cn4[reg] = cn;
          float hn = o_ * htanh(cn);
          *(_Float16*)(bwr + (mm + 4 * h) * 4096 + wbase[reg]) = (_Float16)hn;
        }
        cst[h][j] = cn4;
      }
    }
    lds_barrier();   // lgkmcnt(0) + s_barrier; fold stores stay in flight
  }

  // ---------------- epilogue: final out from h(20) (buf parity 0) ----------------
  {
    float p0 = 0.f, p1 = 0.f;
#pragma unroll
    for (int kt = 0; kt < 4; ++kt) {
      const half8 wf = *(const half8*)(wol + wc * 256 + kt * 64 + lg * 16);
      half8 a0 = *(const half8*)(buf0 + wm * 4096 + arow + ((64 * kt) ^ base0));
      half8 a1 = *(const half8*)(buf0 + (wm + 4) * 4096 + arow + ((64 * kt) ^ base0));
#pragma unroll
      for (int pp = 0; pp < 4; ++pp) {
        half2v wa; wa[0] = wf[2 * pp]; wa[1] = wf[2 * pp + 1];
        half2v h0; h0[0] = a0[2 * pp]; h0[1] = a0[2 * pp + 1];
        half2v h1; h1[0] = a1[2 * pp]; h1[1] = a1[2 * pp + 1];
        p0 = dot2(h0, wa, p0);
        p1 = dot2(h1, wa, p1);
      }
    }
    p0 += __shfl_xor(p0, 16, 64); p0 += __shfl_xor(p0, 32, 64);
    p1 += __shfl_xor(p1, 16, 64); p1 += __shfl_xor(p1, 32, 64);
    if (l < 16) {
      size_t base = (size_t)19 * (RT * 2);
      outp[base + (size_t)(r0 + 16 * wm + l) * 2 + wc] = p0 + bo;
      outp[base + (size_t)(r0 + 64 + 16 * wm + l) * 2 + wc] = p1 + bo;
    }
  }
}

extern "C" void kernel_launch(void* const* d_in, const int* in_sizes, int n_in,
                              void* d_out, int out_size, void* d_ws, size_t ws_size,
                              hipStream_t stream) {
  const float* obs   = (const float*)d_in[0];
  const float* pred  = (const float*)d_in[1];
  const float* Wm1   = (const float*)d_in[2];
  const float* bm1   = (const float*)d_in[3];
  const float* Wm2   = (const float*)d_in[4];
  const float* bm2   = (const float*)d_in[5];
  const float* W_ih  = (const float*)d_in[6];
  const float* W_hh  = (const float*)d_in[7];
  const float* b_ih  = (const float*)d_in[8];
  const float* b_hh  = (const float*)d_in[9];
  const float* W_out = (const float*)d_in[10];
  const float* b_out = (const float*)d_in[11];

  decoder_kernel<<<RT / RB, 512, 0, stream>>>(
      obs, pred, Wm1, bm1, Wm2, bm2, W_ih, W_hh, b_ih, b_hh, W_out, b_out,
      (float*)d_out);
}

// Round 16
// 300.886 us; speedup vs baseline: 1.0590x; 1.0590x over previous
//
#include <hip/hip_runtime.h>

#define NT 20        // time steps
#define BT 4096      // batch
#define HD 128       // hidden
#define RT 81920     // total rows = K*B = 20*4096
#define RB 64        // rows per block

typedef _Float16 half8 __attribute__((ext_vector_type(8)));
typedef _Float16 half2v __attribute__((ext_vector_type(2)));
typedef float f32x4 __attribute__((ext_vector_type(4)));
typedef float f32x2 __attribute__((ext_vector_type(2)));
typedef unsigned u32x4 __attribute__((ext_vector_type(4)));

__device__ __forceinline__ float clamp01(float x) {
  return fminf(fmaxf(x, 0.0f), 1.0f);
}
__device__ __forceinline__ float htanh(float x) {
  return fminf(fmaxf(x, -1.0f), 1.0f);
}

// load 8 consecutive f32, scale, convert to f16x8 fragment
__device__ __forceinline__ half8 ldcvt8s(const float* __restrict__ p, float s) {
  f32x4 a = *(const f32x4*)p;
  f32x4 b = *(const f32x4*)(p + 4);
  half8 r;
  r[0] = (_Float16)(a[0] * s); r[1] = (_Float16)(a[1] * s);
  r[2] = (_Float16)(a[2] * s); r[3] = (_Float16)(a[3] * s);
  r[4] = (_Float16)(b[0] * s); r[5] = (_Float16)(b[1] * s);
  r[6] = (_Float16)(b[2] * s); r[7] = (_Float16)(b[3] * s);
  return r;
}
__device__ __forceinline__ half8 ldcvt8(const float* __restrict__ p) {
  return ldcvt8s(p, 1.0f);
}

// LDS-visibility-only barrier (no vmcnt(0) drain; fold stores stay in flight)
__device__ __forceinline__ void lds_barrier() {
  __builtin_amdgcn_sched_barrier(0);
  asm volatile("s_waitcnt lgkmcnt(0)" ::: "memory");
  __builtin_amdgcn_s_barrier();
  __builtin_amdgcn_sched_barrier(0);
}

// Persistent LSTM decoder, 64 rows/block, 8 waves, launch_bounds (512,2).
// R15 post-mortem: per-step CP scales with work (RB=128 doubled both) =>
// throughput-bound inside the wave-serial chain; revert to RB=64 (R14 base,
// 303.9us). R16 removes the last removable serial segment: the fold's
// 32 fdot2 + TWO serial __shfl_xor (ds_bpermute ~120cyc each, back-to-back
// right before the barrier, every step). out = h @ W_out^T is matmul-shaped
// and the A-frags are live at j==3 => fold via 4 chained MFMAs against
// hoisted W_out B-fragments (cols 0..1 valid, rest zero). MFMA does the
// K-reduction: no cross-lane, no dot2, no wol reads. D-layout lands
// out[col=l15<2][row=4lg+reg] ready for direct store. Each wave computes
// BOTH out columns -> only wc==0 waves fold (wave-uniform; wc==1 waves
// shed their fold work). Same f16->f32 precision as dot2 (absmax 3.9e-3).
// Everything else = R14: bAug/wbase hoists, A[2][5] prefetch, cst[j] regs,
// hsig prefold, XOR-swizzled h dbuf, lds_barrier.
__global__ __launch_bounds__(512, 2) void decoder_kernel(
    const float* __restrict__ obs, const float* __restrict__ pred,
    const float* __restrict__ Wm1, const float* __restrict__ bm1,
    const float* __restrict__ Wm2, const float* __restrict__ bm2,
    const float* __restrict__ W_ih, const float* __restrict__ W_hh,
    const float* __restrict__ b_ih, const float* __restrict__ b_hh,
    const float* __restrict__ W_out, const float* __restrict__ b_out,
    float* __restrict__ outp)
{
  __shared__ __align__(16) char lds[37888];
  const int tid = threadIdx.x;
  const int w   = tid >> 6;       // wave id 0..7
  const int l   = tid & 63;
  const int l15 = l & 15;
  const int lg  = l >> 4;         // lane group 0..3
  const int wm  = w & 3;          // fold m-tile
  const int wc  = w >> 2;         // wc==0 waves do the MFMA-fold
  const int r0  = blockIdx.x * RB;
  const int b0  = r0 & (BT - 1);

  char* const buf0 = lds;             // h buffer parity 0 (16KB)
  char* const h1l  = lds + 16384;     // parity-1 h buffer; aliases MLP mid acts
  char* const obsl = lds + 32768;     // obs staged: [20][64] packed f16x2 (5KB)

  const f32x4 fzero = {0.f, 0.f, 0.f, 0.f};
  const float SCL = 1.0f / 6.0f;

  const int rdmask = (l15 & 7) << 4;
  const int arow  = l15 * 256;              // A-read row byte
  const int base0 = (16 * lg) ^ rdmask;     // A-read k byte; ao[kt]=(64*kt)^base0
  const int wcol2 = 32 * w + 2 * l15;       // h-write col byte (pre-swizzle)

  // h-write addresses hoisted
  int wbase[4];
#pragma unroll
  for (int reg = 0; reg < 4; ++reg) {
    int rr = 4 * lg + reg;
    wbase[reg] = rr * 256 + (wcol2 ^ ((rr & 7) << 4));
  }

  // ---- stage obs (packed f16x2) ----
  for (int i = tid; i < NT * RB; i += 512) {
    int t = i >> 6, row = i & 63;
    int tp = (t > 0) ? t - 1 : 0;
    f32x2 xv = *(const f32x2*)(obs + ((size_t)tp * BT + b0 + row) * 2);
    half2v hp; hp[0] = (_Float16)xv[0]; hp[1] = (_Float16)xv[1];
    *(unsigned*)(obsl + (size_t)i * 4) = __builtin_bit_cast(unsigned, hp);
  }

  // ---------------- Prologue: h0 = MLP(pred) ----------------
  // GEMM1: h1[64x64] = leaky_relu(pred @ Wm1^T + bm1). wave w: m=wm, n=2wc+{0,1}
  {
    half8 a1[4], b1[2][4];
#pragma unroll
    for (int kt = 0; kt < 4; ++kt)
      a1[kt] = ldcvt8(pred + (size_t)(r0 + 16 * wm + l15) * HD + kt * 32 + lg * 8);
#pragma unroll
    for (int j = 0; j < 2; ++j)
#pragma unroll
      for (int kt = 0; kt < 4; ++kt)
        b1[j][kt] = ldcvt8(Wm1 + (l15 + 16 * (2 * wc + j)) * HD + kt * 32 + lg * 8);
    f32x4 acc1[2] = {fzero, fzero};
#pragma unroll
    for (int kt = 0; kt < 4; ++kt)
#pragma unroll
      for (int j = 0; j < 2; ++j)
        acc1[j] = __builtin_amdgcn_mfma_f32_16x16x32_f16(a1[kt], b1[j][kt], acc1[j], 0, 0, 0);
#pragma unroll
    for (int j = 0; j < 2; ++j) {
      int c = l15 + 16 * (2 * wc + j);
      float bb = bm1[c];
#pragma unroll
      for (int reg = 0; reg < 4; ++reg) {
        int row = 16 * wm + 4 * lg + reg;
        float v = acc1[j][reg] + bb;
        v = v >= 0.f ? v : 0.01f * v;
        *(_Float16*)(h1l + row * 128 + ((2 * c) ^ ((row & 7) << 4))) = (_Float16)v;
      }
    }
  }
  __syncthreads();
  // GEMM2: h0[64x128] = h1 @ Wm2^T + bm2 -> buf0. wave w: m=wm, n=4wc+{0..3}
  {
    half8 a2[2], b2[4][2];
#pragma unroll
    for (int kt = 0; kt < 2; ++kt)
      a2[kt] = *(const half8*)(h1l + (16 * wm + l15) * 128 + ((64 * kt + 16 * lg) ^ rdmask));
#pragma unroll
    for (int j = 0; j < 4; ++j)
#pragma unroll
      for (int kt = 0; kt < 2; ++kt)
        b2[j][kt] = ldcvt8(Wm2 + (l15 + 16 * (4 * wc + j)) * 64 + kt * 32 + lg * 8);
    f32x4 acc2[4] = {fzero, fzero, fzero, fzero};
#pragma unroll
    for (int kt = 0; kt < 2; ++kt)
#pragma unroll
      for (int j = 0; j < 4; ++j)
        acc2[j] = __builtin_amdgcn_mfma_f32_16x16x32_f16(a2[kt], b2[j][kt], acc2[j], 0, 0, 0);
#pragma unroll
    for (int j = 0; j < 4; ++j) {
      int c = l15 + 16 * (4 * wc + j);
      float bb = bm2[c];
#pragma unroll
      for (int reg = 0; reg < 4; ++reg) {
        int row = 16 * wm + 4 * lg + reg;
        float v = acc2[j][reg] + bb;
        *(_Float16*)(buf0 + row * 256 + ((2 * c) ^ ((row & 7) << 4))) = (_Float16)v;
      }
    }
  }

  // ---- steady-state per-wave constants ----
  // bW: W_hh fragments (64 regs), i/f/o rows pre-scaled by 1/6 (hsig prefold)
  half8 bW[4][4];
  half8 bAug[4];                    // aug B-fragments (t/j-invariant)
#pragma unroll
  for (int n = 0; n < 4; ++n) {
    const float s = (n == 2) ? 1.0f : SCL;
    int g = 128 * n + 16 * w + l15;
#pragma unroll
    for (int kt = 0; kt < 4; ++kt)
      bW[n][kt] = ldcvt8s(W_hh + (size_t)g * HD + kt * 32 + lg * 8, s);
    half2v t2;
    t2[0] = (_Float16)(W_ih[g * 2 + 0] * s);
    t2[1] = (_Float16)(W_ih[g * 2 + 1] * s);
    float bs = b_ih[g] + b_hh[g];
    half2v t3;
    t3[0] = (_Float16)((n == 2) ? bs : bs * SCL + 0.5f);
    t3[1] = (_Float16)0.0f;
    unsigned v0 = (lg == 0) ? __builtin_bit_cast(unsigned, t2) : 0u;
    unsigned v1 = (lg == 0) ? __builtin_bit_cast(unsigned, t3) : 0u;
    u32x4 bu = {v0, v1, 0u, 0u};
    bAug[n] = __builtin_bit_cast(half8, bu);
  }

  // W_out B-fragments for the MFMA-fold: col l15 (<2 valid, else zero)
  half8 bOut[4];
  {
    const half8 hz = {};
    int c2 = (l15 < 2) ? l15 : 0;   // clamp address to valid row
#pragma unroll
    for (int kt = 0; kt < 4; ++kt) {
      half8 v = ldcvt8(W_out + c2 * HD + kt * 32 + lg * 8);
      bOut[kt] = (l15 < 2) ? v : hz;
    }
  }
  const float bo0 = b_out[0], bo1 = b_out[1];

  // c-state in registers, indexed by j (compile-time; rotation fixed)
  f32x4 cst[4] = {fzero, fzero, fzero, fzero};

  __syncthreads();  // h0/obs visible; h1l reads done (step0 writes alias)

  // ---------------- 20 recurrent steps ----------------
  for (int t = 0; t < NT; ++t) {
    char* const brd = lds + ((t & 1) << 14);
    char* const bwr = lds + (((t & 1) ^ 1) << 14);

    half8 A[2][5];   // A-fragment double buffer; j unrolled -> static idx

    // prefetch j=0 tile (mm = wm+1)
    {
      const int mm0 = (wm + 1) & 3;
#pragma unroll
      for (int kt = 0; kt < 4; ++kt)
        A[0][kt] = *(const half8*)(brd + mm0 * 4096 + arow + ((64 * kt) ^ base0));
      unsigned xv = *(const unsigned*)(obsl + ((t << 6) + (mm0 << 4) + l15) * 4);
      unsigned u0 = (lg == 0) ? xv : 0u;
      unsigned u1 = (lg == 0) ? 0x00003C00u : 0u;  // f16 1.0 in elem 2
      u32x4 xu = {u0, u1, 0u, 0u};
      A[0][4] = __builtin_bit_cast(half8, xu);
    }

#pragma unroll
    for (int j = 0; j < 4; ++j) {
      const int mm = (wm + 1 + j) & 3;   // fold tile (mm==wm) at j==3
      const int cur = j & 1;

      // prefetch NEXT tile's A-fragments before this tile's MFMA cluster
      if (j < 3) {
        const int mn = (wm + 2 + j) & 3;
#pragma unroll
        for (int kt = 0; kt < 4; ++kt)
          A[cur ^ 1][kt] = *(const half8*)(brd + mn * 4096 + arow + ((64 * kt) ^ base0));
        unsigned xv = *(const unsigned*)(obsl + ((t << 6) + (mn << 4) + l15) * 4);
        unsigned u0 = (lg == 0) ? xv : 0u;
        unsigned u1 = (lg == 0) ? 0x00003C00u : 0u;
        u32x4 xu = {u0, u1, 0u, 0u};
        A[cur ^ 1][4] = __builtin_bit_cast(half8, xu);
      }

      // MFMA cluster (single acc bank)
      f32x4 acc[4] = {fzero, fzero, fzero, fzero};
      __builtin_amdgcn_s_setprio(1);
#pragma unroll
      for (int kt = 0; kt < 5; ++kt) {
#pragma unroll
        for (int n = 0; n < 4; ++n) {
          const half8 bfrag = (kt < 4) ? bW[n][kt] : bAug[n];
          acc[n] = __builtin_amdgcn_mfma_f32_16x16x32_f16(A[cur][kt], bfrag, acc[n], 0, 0, 0);
        }
      }
      __builtin_amdgcn_s_setprio(0);

      // MFMA-fold at j==3 (mm==wm), wc==0 waves: out[t-1] = h(t-1) @ W_out^T
      // (no aug tile: x/bias don't contribute). No cross-lane, no dot2.
      if (j == 3 && t > 0 && wc == 0) {
        f32x4 accF = fzero;
#pragma unroll
        for (int kt = 0; kt < 4; ++kt)
          accF = __builtin_amdgcn_mfma_f32_16x16x32_f16(A[cur][kt], bOut[kt], accF, 0, 0, 0);
        if (l15 < 2) {
          size_t base = (size_t)(t - 1) * (RT * 2);
          float bo = l15 ? bo1 : bo0;
#pragma unroll
          for (int reg = 0; reg < 4; ++reg)
            outp[base + (size_t)(r0 + 16 * wm + 4 * lg + reg) * 2 + l15] = accF[reg] + bo;
        }
      }

      // fused LSTM update for this tile (lane-local), cst[j] compile-time
      f32x4 cn4;
#pragma unroll
      for (int reg = 0; reg < 4; ++reg) {
        float i_ = clamp01(acc[0][reg]);
        float f_ = clamp01(acc[1][reg]);
        float g_ = htanh(acc[2][reg]);
        float o_ = clamp01(acc[3][reg]);
        float cn = fmaf(f_, cst[j][reg], i_ * g_);
        cn4[reg] = cn;
        float hn = o_ * htanh(cn);
        *(_Float16*)(bwr + mm * 4096 + wbase[reg]) = (_Float16)hn;
      }
      cst[j] = cn4;
    }
    lds_barrier();   // lgkmcnt(0) + s_barrier; fold stores stay in flight
  }

  // ---------------- epilogue: out[19] from h(20) (buf parity 0) ----------------
  if (wc == 0) {
    f32x4 accF = fzero;
#pragma unroll
    for (int kt = 0; kt < 4; ++kt) {
      half8 a = *(const half8*)(buf0 + wm * 4096 + arow + ((64 * kt) ^ base0));
      accF = __builtin_amdgcn_mfma_f32_16x16x32_f16(a, bOut[kt], accF, 0, 0, 0);
    }
    if (l15 < 2) {
      size_t base = (size_t)19 * (RT * 2);
      float bo = l15 ? bo1 : bo0;
#pragma unroll
      for (int reg = 0; reg < 4; ++reg)
        outp[base + (size_t)(r0 + 16 * wm + 4 * lg + reg) * 2 + l15] = accF[reg] + bo;
    }
  }
}

extern "C" void kernel_launch(void* const* d_in, const int* in_sizes, int n_in,
                              void* d_out, int out_size, void* d_ws, size_t ws_size,
                              hipStream_t stream) {
  const float* obs   = (const float*)d_in[0];
  const float* pred  = (const float*)d_in[1];
  const float* Wm1   = (const float*)d_in[2];
  const float* bm1   = (const float*)d_in[3];
  const float* Wm2   = (const float*)d_in[4];
  const float* bm2   = (const float*)d_in[5];
  const float* W_ih  = (const float*)d_in[6];
  const float* W_hh  = (const float*)d_in[7];
  const float* b_ih  = (const float*)d_in[8];
  const float* b_hh  = (const float*)d_in[9];
  const float* W_out = (const float*)d_in[10];
  const float* b_out = (const float*)d_in[11];

  decoder_kernel<<<RT / RB, 512, 0, stream>>>(
      obs, pred, Wm1, bm1, Wm2, bm2, W_ih, W_hh, b_ih, b_hh, W_out, b_out,
      (float*)d_out);
}

// Round 17
// 285.753 us; speedup vs baseline: 1.1151x; 1.0530x over previous
//
#include <hip/hip_runtime.h>

#define NT 20        // time steps
#define BT 4096      // batch
#define HD 128       // hidden
#define RT 81920     // total rows = K*B = 20*4096
#define RB 64        // rows per block

typedef _Float16 half8 __attribute__((ext_vector_type(8)));
typedef _Float16 half2v __attribute__((ext_vector_type(2)));
typedef float f32x4 __attribute__((ext_vector_type(4)));
typedef float f32x2 __attribute__((ext_vector_type(2)));
typedef unsigned u32x4 __attribute__((ext_vector_type(4)));

__device__ __forceinline__ float clamp01(float x) {
  return fminf(fmaxf(x, 0.0f), 1.0f);
}
__device__ __forceinline__ float htanh(float x) {
  return fminf(fmaxf(x, -1.0f), 1.0f);
}

// load 8 consecutive f32, scale, convert to f16x8 fragment
__device__ __forceinline__ half8 ldcvt8s(const float* __restrict__ p, float s) {
  f32x4 a = *(const f32x4*)p;
  f32x4 b = *(const f32x4*)(p + 4);
  half8 r;
  r[0] = (_Float16)(a[0] * s); r[1] = (_Float16)(a[1] * s);
  r[2] = (_Float16)(a[2] * s); r[3] = (_Float16)(a[3] * s);
  r[4] = (_Float16)(b[0] * s); r[5] = (_Float16)(b[1] * s);
  r[6] = (_Float16)(b[2] * s); r[7] = (_Float16)(b[3] * s);
  return r;
}
__device__ __forceinline__ half8 ldcvt8(const float* __restrict__ p) {
  return ldcvt8s(p, 1.0f);
}

// LDS-visibility-only barrier (no vmcnt(0) drain; fold stores stay in
// flight). Trailing sched_barrier only (rule #18: fence AFTER the lgkmcnt
// so reg-only ops can't hoist past it); leading one dropped so next-step
// address VALU can fill the barrier shadow.
__device__ __forceinline__ void lds_barrier() {
  asm volatile("s_waitcnt lgkmcnt(0)" ::: "memory");
  __builtin_amdgcn_s_barrier();
  __builtin_amdgcn_sched_barrier(0);
}

// Persistent LSTM decoder, 64 rows/block, 8 waves, launch_bounds (512,2).
// R17 (final trims on the R16 structure, zero numeric change):
//  1. s_setprio REMOVED — m190 measured it hurts barrier-lockstep GEMM
//  2. t-loop unrolled x2 — brd/bwr compile-time, no per-step ptr swizzle
//  3. lds_barrier keeps only the trailing sched_barrier
// Structure (verified absmax 3.9e-3): wave w owns hidden slice [16w,16w+16);
// gate cols 128n+16w+(l&15) lane-local in mfma 16x16x32 D-layout. h: LDS
// f16 dbuf, swizzle byte^=(row&7)<<4. c: regs cst[j] (compile-time, fixed
// rotation mm=(wm+1+j)&3). hsig prefold (i/f/o rows x1/6, bias b/6+0.5).
// gi via 5th aug MFMA K-tile. out-fold via 4 chained MFMAs vs bOut at
// j==3 on wc==0 waves (D-layout lands rows ready for direct store).
__global__ __launch_bounds__(512, 2) void decoder_kernel(
    const float* __restrict__ obs, const float* __restrict__ pred,
    const float* __restrict__ Wm1, const float* __restrict__ bm1,
    const float* __restrict__ Wm2, const float* __restrict__ bm2,
    const float* __restrict__ W_ih, const float* __restrict__ W_hh,
    const float* __restrict__ b_ih, const float* __restrict__ b_hh,
    const float* __restrict__ W_out, const float* __restrict__ b_out,
    float* __restrict__ outp)
{
  __shared__ __align__(16) char lds[37888];
  const int tid = threadIdx.x;
  const int w   = tid >> 6;       // wave id 0..7
  const int l   = tid & 63;
  const int l15 = l & 15;
  const int lg  = l >> 4;         // lane group 0..3
  const int wm  = w & 3;          // fold m-tile
  const int wc  = w >> 2;         // wc==0 waves do the MFMA-fold
  const int r0  = blockIdx.x * RB;
  const int b0  = r0 & (BT - 1);

  char* const buf0 = lds;             // h buffer parity 0 (16KB)
  char* const buf1 = lds + 16384;     // h buffer parity 1; aliases MLP mid acts
  char* const h1l  = buf1;
  char* const obsl = lds + 32768;     // obs staged: [20][64] packed f16x2 (5KB)

  const f32x4 fzero = {0.f, 0.f, 0.f, 0.f};
  const float SCL = 1.0f / 6.0f;

  const int rdmask = (l15 & 7) << 4;
  const int arow  = l15 * 256;              // A-read row byte
  const int base0 = (16 * lg) ^ rdmask;     // A-read k byte; ao[kt]=(64*kt)^base0
  const int wcol2 = 32 * w + 2 * l15;       // h-write col byte (pre-swizzle)

  // h-write addresses hoisted
  int wbase[4];
#pragma unroll
  for (int reg = 0; reg < 4; ++reg) {
    int rr = 4 * lg + reg;
    wbase[reg] = rr * 256 + (wcol2 ^ ((rr & 7) << 4));
  }

  // ---- stage obs (packed f16x2) ----
  for (int i = tid; i < NT * RB; i += 512) {
    int t = i >> 6, row = i & 63;
    int tp = (t > 0) ? t - 1 : 0;
    f32x2 xv = *(const f32x2*)(obs + ((size_t)tp * BT + b0 + row) * 2);
    half2v hp; hp[0] = (_Float16)xv[0]; hp[1] = (_Float16)xv[1];
    *(unsigned*)(obsl + (size_t)i * 4) = __builtin_bit_cast(unsigned, hp);
  }

  // ---------------- Prologue: h0 = MLP(pred) ----------------
  // GEMM1: h1[64x64] = leaky_relu(pred @ Wm1^T + bm1). wave w: m=wm, n=2wc+{0,1}
  {
    half8 a1[4], b1[2][4];
#pragma unroll
    for (int kt = 0; kt < 4; ++kt)
      a1[kt] = ldcvt8(pred + (size_t)(r0 + 16 * wm + l15) * HD + kt * 32 + lg * 8);
#pragma unroll
    for (int j = 0; j < 2; ++j)
#pragma unroll
      for (int kt = 0; kt < 4; ++kt)
        b1[j][kt] = ldcvt8(Wm1 + (l15 + 16 * (2 * wc + j)) * HD + kt * 32 + lg * 8);
    f32x4 acc1[2] = {fzero, fzero};
#pragma unroll
    for (int kt = 0; kt < 4; ++kt)
#pragma unroll
      for (int j = 0; j < 2; ++j)
        acc1[j] = __builtin_amdgcn_mfma_f32_16x16x32_f16(a1[kt], b1[j][kt], acc1[j], 0, 0, 0);
#pragma unroll
    for (int j = 0; j < 2; ++j) {
      int c = l15 + 16 * (2 * wc + j);
      float bb = bm1[c];
#pragma unroll
      for (int reg = 0; reg < 4; ++reg) {
        int row = 16 * wm + 4 * lg + reg;
        float v = acc1[j][reg] + bb;
        v = v >= 0.f ? v : 0.01f * v;
        *(_Float16*)(h1l + row * 128 + ((2 * c) ^ ((row & 7) << 4))) = (_Float16)v;
      }
    }
  }
  __syncthreads();
  // GEMM2: h0[64x128] = h1 @ Wm2^T + bm2 -> buf0. wave w: m=wm, n=4wc+{0..3}
  {
    half8 a2[2], b2[4][2];
#pragma unroll
    for (int kt = 0; kt < 2; ++kt)
      a2[kt] = *(const half8*)(h1l + (16 * wm + l15) * 128 + ((64 * kt + 16 * lg) ^ rdmask));
#pragma unroll
    for (int j = 0; j < 4; ++j)
#pragma unroll
      for (int kt = 0; kt < 2; ++kt)
        b2[j][kt] = ldcvt8(Wm2 + (l15 + 16 * (4 * wc + j)) * 64 + kt * 32 + lg * 8);
    f32x4 acc2[4] = {fzero, fzero, fzero, fzero};
#pragma unroll
    for (int kt = 0; kt < 2; ++kt)
#pragma unroll
      for (int j = 0; j < 4; ++j)
        acc2[j] = __builtin_amdgcn_mfma_f32_16x16x32_f16(a2[kt], b2[j][kt], acc2[j], 0, 0, 0);
#pragma unroll
    for (int j = 0; j < 4; ++j) {
      int c = l15 + 16 * (4 * wc + j);
      float bb = bm2[c];
#pragma unroll
      for (int reg = 0; reg < 4; ++reg) {
        int row = 16 * wm + 4 * lg + reg;
        float v = acc2[j][reg] + bb;
        *(_Float16*)(buf0 + row * 256 + ((2 * c) ^ ((row & 7) << 4))) = (_Float16)v;
      }
    }
  }

  // ---- steady-state per-wave constants ----
  half8 bW[4][4];
  half8 bAug[4];                    // aug B-fragments (t/j-invariant)
#pragma unroll
  for (int n = 0; n < 4; ++n) {
    const float s = (n == 2) ? 1.0f : SCL;
    int g = 128 * n + 16 * w + l15;
#pragma unroll
    for (int kt = 0; kt < 4; ++kt)
      bW[n][kt] = ldcvt8s(W_hh + (size_t)g * HD + kt * 32 + lg * 8, s);
    half2v t2;
    t2[0] = (_Float16)(W_ih[g * 2 + 0] * s);
    t2[1] = (_Float16)(W_ih[g * 2 + 1] * s);
    float bs = b_ih[g] + b_hh[g];
    half2v t3;
    t3[0] = (_Float16)((n == 2) ? bs : bs * SCL + 0.5f);
    t3[1] = (_Float16)0.0f;
    unsigned v0 = (lg == 0) ? __builtin_bit_cast(unsigned, t2) : 0u;
    unsigned v1 = (lg == 0) ? __builtin_bit_cast(unsigned, t3) : 0u;
    u32x4 bu = {v0, v1, 0u, 0u};
    bAug[n] = __builtin_bit_cast(half8, bu);
  }

  // W_out B-fragments for the MFMA-fold: col l15 (<2 valid, else zero)
  half8 bOut[4];
  {
    const half8 hz = {};
    int c2 = (l15 < 2) ? l15 : 0;
#pragma unroll
    for (int kt = 0; kt < 4; ++kt) {
      half8 v = ldcvt8(W_out + c2 * HD + kt * 32 + lg * 8);
      bOut[kt] = (l15 < 2) ? v : hz;
    }
  }
  const float bo0 = b_out[0], bo1 = b_out[1];

  // c-state in registers, indexed by j (compile-time; rotation fixed)
  f32x4 cst[4] = {fzero, fzero, fzero, fzero};

  __syncthreads();  // h0/obs visible; h1l reads done (step0 writes alias)

  // ---------------- 20 recurrent steps, unrolled x2 ----------------
#pragma unroll 1
  for (int tt = 0; tt < NT; tt += 2) {
#pragma unroll
    for (int half = 0; half < 2; ++half) {
      const int t = tt + half;
      char* const brd = half ? buf1 : buf0;   // compile-time per unroll copy
      char* const bwr = half ? buf0 : buf1;

      half8 A[2][5];   // A-fragment double buffer; j unrolled -> static idx

      // prefetch j=0 tile (mm = wm+1)
      {
        const int mm0 = (wm + 1) & 3;
#pragma unroll
        for (int kt = 0; kt < 4; ++kt)
          A[0][kt] = *(const half8*)(brd + mm0 * 4096 + arow + ((64 * kt) ^ base0));
        unsigned xv = *(const unsigned*)(obsl + ((t << 6) + (mm0 << 4) + l15) * 4);
        unsigned u0 = (lg == 0) ? xv : 0u;
        unsigned u1 = (lg == 0) ? 0x00003C00u : 0u;  // f16 1.0 in elem 2
        u32x4 xu = {u0, u1, 0u, 0u};
        A[0][4] = __builtin_bit_cast(half8, xu);
      }

#pragma unroll
      for (int j = 0; j < 4; ++j) {
        const int mm = (wm + 1 + j) & 3;   // fold tile (mm==wm) at j==3
        const int cur = j & 1;

        // prefetch NEXT tile's A-fragments before this tile's MFMA cluster
        if (j < 3) {
          const int mn = (wm + 2 + j) & 3;
#pragma unroll
          for (int kt = 0; kt < 4; ++kt)
            A[cur ^ 1][kt] = *(const half8*)(brd + mn * 4096 + arow + ((64 * kt) ^ base0));
          unsigned xv = *(const unsigned*)(obsl + ((t << 6) + (mn << 4) + l15) * 4);
          unsigned u0 = (lg == 0) ? xv : 0u;
          unsigned u1 = (lg == 0) ? 0x00003C00u : 0u;
          u32x4 xu = {u0, u1, 0u, 0u};
          A[cur ^ 1][4] = __builtin_bit_cast(half8, xu);
        }

        // MFMA cluster (single acc bank)
        f32x4 acc[4] = {fzero, fzero, fzero, fzero};
#pragma unroll
        for (int kt = 0; kt < 5; ++kt) {
#pragma unroll
          for (int n = 0; n < 4; ++n) {
            const half8 bfrag = (kt < 4) ? bW[n][kt] : bAug[n];
            acc[n] = __builtin_amdgcn_mfma_f32_16x16x32_f16(A[cur][kt], bfrag, acc[n], 0, 0, 0);
          }
        }

        // MFMA-fold at j==3 (mm==wm), wc==0 waves: out[t-1] = h(t-1) @ W_out^T
        if (j == 3 && t > 0 && wc == 0) {
          f32x4 accF = fzero;
#pragma unroll
          for (int kt = 0; kt < 4; ++kt)
            accF = __builtin_amdgcn_mfma_f32_16x16x32_f16(A[cur][kt], bOut[kt], accF, 0, 0, 0);
          if (l15 < 2) {
            size_t base = (size_t)(t - 1) * (RT * 2);
            float bo = l15 ? bo1 : bo0;
#pragma unroll
            for (int reg = 0; reg < 4; ++reg)
              outp[base + (size_t)(r0 + 16 * wm + 4 * lg + reg) * 2 + l15] = accF[reg] + bo;
          }
        }

        // fused LSTM update for this tile (lane-local), cst[j] compile-time
        f32x4 cn4;
#pragma unroll
        for (int reg = 0; reg < 4; ++reg) {
          float i_ = clamp01(acc[0][reg]);
          float f_ = clamp01(acc[1][reg]);
          float g_ = htanh(acc[2][reg]);
          float o_ = clamp01(acc[3][reg]);
          float cn = fmaf(f_, cst[j][reg], i_ * g_);
          cn4[reg] = cn;
          float hn = o_ * htanh(cn);
          *(_Float16*)(bwr + mm * 4096 + wbase[reg]) = (_Float16)hn;
        }
        cst[j] = cn4;
      }
      lds_barrier();   // lgkmcnt(0) + s_barrier; fold stores stay in flight
    }
  }

  // ---------------- epilogue: out[19] from h(20) (buf parity 0) ----------------
  if (wc == 0) {
    f32x4 accF = fzero;
#pragma unroll
    for (int kt = 0; kt < 4; ++kt) {
      half8 a = *(const half8*)(buf0 + wm * 4096 + arow + ((64 * kt) ^ base0));
      accF = __builtin_amdgcn_mfma_f32_16x16x32_f16(a, bOut[kt], accF, 0, 0, 0);
    }
    if (l15 < 2) {
      size_t base = (size_t)19 * (RT * 2);
      float bo = l15 ? bo1 : bo0;
#pragma unroll
      for (int reg = 0; reg < 4; ++reg)
        outp[base + (size_t)(r0 + 16 * wm + 4 * lg + reg) * 2 + l15] = accF[reg] + bo;
    }
  }
}

extern "C" void kernel_launch(void* const* d_in, const int* in_sizes, int n_in,
                              void* d_out, int out_size, void* d_ws, size_t ws_size,
                              hipStream_t stream) {
  const float* obs   = (const float*)d_in[0];
  const float* pred  = (const float*)d_in[1];
  const float* Wm1   = (const float*)d_in[2];
  const float* bm1   = (const float*)d_in[3];
  const float* Wm2   = (const float*)d_in[4];
  const float* bm2   = (const float*)d_in[5];
  const float* W_ih  = (const float*)d_in[6];
  const float* W_hh  = (const float*)d_in[7];
  const float* b_ih  = (const float*)d_in[8];
  const float* b_hh  = (const float*)d_in[9];
  const float* W_out = (const float*)d_in[10];
  const float* b_out = (const float*)d_in[11];

  decoder_kernel<<<RT / RB, 512, 0, stream>>>(
      obs, pred, Wm1, bm1, Wm2, bm2, W_ih, W_hh, b_ih, b_hh, W_out, b_out,
      (float*)d_out);
}